// Round 1
// 772.881 us; speedup vs baseline: 1.2889x; 1.2889x over previous
//
#include <hip/hip_runtime.h>
#include <stdint.h>

#define VOCAB 32000
#define MDIM  2048     // B*T
#define KDIM  1024     // E
#define RANK  32
#define TT    512
#define INV_LN2 1.4426950408889634f
#define LN2     0.6931471805599453f
#define CH    8        // scan steps folded per chunk
#define NCH   64       // chunks per batch (ceil(511/8))
#define NSUP  8        // chunk matrices folded per super matrix

typedef __attribute__((ext_vector_type(8))) __bf16 bf16x8;
typedef __attribute__((ext_vector_type(4))) float f32x4;

__device__ __forceinline__ void async_cp16(void* lds, const void* g) {
  __builtin_amdgcn_global_load_lds(
      (const __attribute__((address_space(1))) void*)g,
      (__attribute__((address_space(3))) void*)lds, 16, 0, 0);
}

__device__ __forceinline__ float fast_exp2(float x) {
#if __has_builtin(__builtin_amdgcn_exp2f)
  return __builtin_amdgcn_exp2f(x);
#else
  return exp2f(x);
#endif
}
__device__ __forceinline__ float fast_log2(float x) {
#if __has_builtin(__builtin_amdgcn_logf)
  return __builtin_amdgcn_logf(x);
#else
  return log2f(x);
#endif
}

__device__ __forceinline__ unsigned short f2bf(float f) {
  unsigned u = __float_as_uint(f);
  unsigned r = (u + 0x7FFFu + ((u >> 16) & 1u)) >> 16;  // RNE
  return (unsigned short)r;
}

// ---------------- K0: f32 -> bf16 convert ----------------
__global__ void cvt_bf16_k(const float* __restrict__ src,
                           unsigned short* __restrict__ dst, int n4) {
  int i = blockIdx.x * blockDim.x + threadIdx.x;
  if (i >= n4) return;
  float4 v = ((const float4*)src)[i];
  ushort4 o;
  o.x = f2bf(v.x); o.y = f2bf(v.y); o.z = f2bf(v.z); o.w = f2bf(v.w);
  ((ushort4*)dst)[i] = o;
}

// ---------------- K1: logits = A @ W^T + b (bf16 MFMA, m97 structure) ------
__global__ __launch_bounds__(256) void gemm_bt_k(
    const unsigned short* __restrict__ A,   // [2048][1024] bf16
    const unsigned short* __restrict__ Bw,  // [32000][1024] bf16
    const float* __restrict__ bias,
    float* __restrict__ C)                  // [2048][32000] f32
{
  __shared__ unsigned short As[128 * 64];
  __shared__ unsigned short Bs[128 * 64];
  int tid  = threadIdx.x;
  int lane = tid & 63;
  int wave = tid >> 6;
  int wm = wave >> 1, wn = wave & 1;
  int m0 = blockIdx.y * 128;
  int n0 = blockIdx.x * 128;

  f32x4 acc[4][4];
#pragma unroll
  for (int i = 0; i < 4; i++)
#pragma unroll
    for (int j = 0; j < 4; j++) acc[i][j] = (f32x4){0.f, 0.f, 0.f, 0.f};

  for (int k0 = 0; k0 < KDIM; k0 += 64) {
    __syncthreads();  // previous iter's LDS reads done before restage
#pragma unroll
    for (int i = 0; i < 4; i++) {
      int ci  = tid + 256 * i;      // 16B chunk id, lane-contiguous for LDS dest
      int row = ci >> 3;
      int kc  = (ci & 7) << 3;
      async_cp16(As + ci * 8, A  + (size_t)(m0 + row) * KDIM + k0 + kc);
      async_cp16(Bs + ci * 8, Bw + (size_t)(n0 + row) * KDIM + k0 + kc);
    }
    __syncthreads();  // staging complete (compiler drains vmcnt)
#pragma unroll
    for (int kk = 0; kk < 64; kk += 32) {
      bf16x8 af[4], bfr[4];
      int kidx = kk + (lane >> 4) * 8;
#pragma unroll
      for (int im = 0; im < 4; im++) {
        int m = wm * 64 + im * 16 + (lane & 15);
        af[im] = *(const bf16x8*)(As + m * 64 + kidx);
      }
#pragma unroll
      for (int in = 0; in < 4; in++) {
        int n = wn * 64 + in * 16 + (lane & 15);
        bfr[in] = *(const bf16x8*)(Bs + n * 64 + kidx);
      }
#pragma unroll
      for (int im = 0; im < 4; im++)
#pragma unroll
        for (int in = 0; in < 4; in++)
          acc[im][in] = __builtin_amdgcn_mfma_f32_16x16x32_bf16(
              af[im], bfr[in], acc[im][in], 0, 0, 0);
    }
  }
  // epilogue: C/D layout col=lane&15, row=(lane>>4)*4+reg  [m89-verified]
  int cl = lane & 15;
  int rq = (lane >> 4) * 4;
  float bv[4];
#pragma unroll
  for (int in = 0; in < 4; in++) bv[in] = bias[n0 + wn * 64 + in * 16 + cl];
#pragma unroll
  for (int im = 0; im < 4; im++) {
#pragma unroll
    for (int r = 0; r < 4; r++) {
      int m = m0 + wm * 64 + im * 16 + rq + r;
      float* Crow = C + (size_t)m * VOCAB + n0 + wn * 64;
#pragma unroll
      for (int in = 0; in < 4; in++)
        Crow[in * 16 + cl] = acc[im][in][r] + bv[in];
    }
  }
}

// ---------------- K2: top-64 per row, target forced ----------------
#define CAP 1024
__global__ __launch_bounds__(256) void topk_k(
    const float* __restrict__ logits, const int* __restrict__ target,
    int* __restrict__ beam_idx, float* __restrict__ beam_emit2,
    float* __restrict__ emit_tgt)
{
  __shared__ unsigned long long packs[CAP];
  __shared__ int ncand;
  int r   = blockIdx.x;  // 0..2047 = b*512+t
  int tid = threadIdx.x;
  const float* row = logits + (size_t)r * VOCAB;
  int tgt = target[r];
  if (tid == 0) ncand = 0;
  for (int i = tid; i < CAP; i += 256) packs[i] = 0ull;
  __syncthreads();

  const float TH = 1.45f;
  for (int i = tid * 4; i < VOCAB; i += 1024) {
    float4 v = *(const float4*)(row + i);
#pragma unroll
    for (int j = 0; j < 4; j++) {
      float f = (&v.x)[j];
      int idx = i + j;
      if (f > TH || idx == tgt) {
        unsigned key = __float_as_uint(f);
        key = (key & 0x80000000u) ? ~key : (key | 0x80000000u);
        if (idx == tgt) key = 0xFFFFFFFFu;  // forced inf
        int p = atomicAdd(&ncand, 1);
        if (p < CAP) packs[p] = ((unsigned long long)key << 32) | (unsigned)idx;
      }
    }
  }
  __syncthreads();
  // bitonic sort descending (pad key 0 sorts last)
  for (unsigned k = 2; k <= CAP; k <<= 1) {
    for (unsigned j = k >> 1; j > 0; j >>= 1) {
      for (int i = tid; i < CAP; i += 256) {
        int ixj = i ^ (int)j;
        if (ixj > i) {
          unsigned long long a = packs[i], c = packs[ixj];
          bool up = ((i & k) == 0);
          if (up ? (a < c) : (a > c)) { packs[i] = c; packs[ixj] = a; }
        }
      }
      __syncthreads();
    }
  }
  if (tid < 64) {
    unsigned long long pk = packs[tid];
    unsigned key = (unsigned)(pk >> 32);
    int idx = (int)(pk & 0xFFFFFFFFu);
    float v;
    if (key == 0xFFFFFFFFu) v = row[tgt];          // true logit at target
    else if (key == 0u)     { v = -1e30f; idx = 0; }  // impossible pad
    else {
      unsigned u = (key & 0x80000000u) ? (key & 0x7FFFFFFFu) : ~key;
      v = __uint_as_float(u);
    }
    beam_idx[r * 64 + tid]  = idx;
    beam_emit2[r * 64 + tid] = v * INV_LN2;  // log2 domain
  }
  if (tid == 0) emit_tgt[r] = row[tgt];
}

// ---------------- K3: tm2[b][t-1][p][n] = dot(E1[beam(t-1,p)], E2[beam(t,n)])/ln2
__global__ __launch_bounds__(256) void trans_k(
    const float* __restrict__ E1, const float* __restrict__ E2,
    const int* __restrict__ beam_idx, float* __restrict__ tm2)
{
  __shared__ float e1[64][33];  // +1 pad: conflict-free column reads
  __shared__ float e2[64][33];
  int x = blockIdx.x;            // 0..2043
  int b = x / 511;
  int t = 1 + (x % 511);
  int tid = threadIdx.x;
  {
    int rowi = tid >> 2, seg = tid & 3;
    int i1 = beam_idx[(b * TT + (t - 1)) * 64 + rowi];
    int i2 = beam_idx[(b * TT + t) * 64 + rowi];
    const float4* p1 = (const float4*)(E1 + (size_t)i1 * RANK);
    const float4* p2 = (const float4*)(E2 + (size_t)i2 * RANK);
    float4 a0 = p1[seg * 2], a1 = p1[seg * 2 + 1];
    float4 c0 = p2[seg * 2], c1 = p2[seg * 2 + 1];
    int c = seg * 8;
    e1[rowi][c+0]=a0.x; e1[rowi][c+1]=a0.y; e1[rowi][c+2]=a0.z; e1[rowi][c+3]=a0.w;
    e1[rowi][c+4]=a1.x; e1[rowi][c+5]=a1.y; e1[rowi][c+6]=a1.z; e1[rowi][c+7]=a1.w;
    e2[rowi][c+0]=c0.x; e2[rowi][c+1]=c0.y; e2[rowi][c+2]=c0.z; e2[rowi][c+3]=c0.w;
    e2[rowi][c+4]=c1.x; e2[rowi][c+5]=c1.y; e2[rowi][c+6]=c1.z; e2[rowi][c+7]=c1.w;
  }
  __syncthreads();
  int n = tid & 63;
  float re2[RANK];
#pragma unroll
  for (int k = 0; k < RANK; k++) re2[k] = e2[n][k];
  float* out = tm2 + (size_t)(b * 511 + (t - 1)) * 4096;
#pragma unroll
  for (int i = 0; i < 16; i++) {
    int p = (tid >> 6) * 16 + i;   // wave-uniform -> LDS broadcast
    float s = 0.f;
#pragma unroll
    for (int k = 0; k < RANK; k++) s += e1[p][k] * re2[k];
    out[p * 64 + n] = s * INV_LN2;
  }
}

// ====================== K4: parallel CRF scan ===========================
// The logsumexp recurrence is an associative scan under the (max-rescaled)
// exp-domain matrix product.  Old crf_scan_k streamed 16 KB/step into ONE
// CU (1580 cy/step, measured 657 ns/step -> 336 us).  New structure:
//   K4a crf_chunk_k : 256 blocks fold 8 steps each into a chunk matrix
//   K4b crf_super_k : 32 blocks fold 8 chunk matrices -> super matrices
//   K4c crf_final_k : 4 blocks, numerator + 8 matvec steps + logsumexp
// All matmuls are plain f32 (no f32 MFMA on CDNA4; VALU at 2048 cy/CU per
// 64^3 product).  Per-matmul renorm: scale by 2^-(maxexp) tracked in Lacc.

// staging mapping: thread handles 16 consecutive floats at linear idx tid*16
// i.e. row r=tid>>2, float4 chunks c4..c4+3 where c4=(tid&3)*4.
// Ms is stored with chunk index XOR ((r>>2)&3)   [kills 4-way bank conflict
// on the 4 simultaneous per-wave row reads, rows 1024B apart = same banks]

__device__ __forceinline__ void stage_exp(const float* __restrict__ tmrow,
                                          const float* __restrict__ berow,
                                          f32x4* dst4, int tid, int swz) {
  int r  = tid >> 2;
  int c4 = (tid & 3) * 4;
  int sw = swz ? ((r >> 2) & 3) : 0;
  const f32x4* src  = (const f32x4*)(tmrow + r * 64);
  const f32x4* bsrc = (const f32x4*)berow;
#pragma unroll
  for (int q = 0; q < 4; q++) {
    f32x4 v  = src[c4 + q];
    f32x4 be = bsrc[c4 + q];
    f32x4 o;
    o[0] = fast_exp2(v[0] + be[0]);
    o[1] = fast_exp2(v[1] + be[1]);
    o[2] = fast_exp2(v[2] + be[2]);
    o[3] = fast_exp2(v[3] + be[3]);
    dst4[r * 16 + ((c4 + q) ^ sw)] = o;
  }
}

__device__ __forceinline__ void stage_copy_swz(const float* __restrict__ src,
                                               f32x4* dst4, int tid) {
  int r  = tid >> 2;
  int c4 = (tid & 3) * 4;
  int sw = (r >> 2) & 3;
  const f32x4* s4 = (const f32x4*)(src + r * 64);
#pragma unroll
  for (int q = 0; q < 4; q++) dst4[r * 16 + ((c4 + q) ^ sw)] = s4[c4 + q];
}

// Ms <- renorm(Ms @ Ts); returns log2 scale consumed. Caller must have
// issued __syncthreads() after staging Ts (and reset sE[par^1]).
__device__ __forceinline__ float mm_renorm(f32x4* Ms4, const f32x4* Ts4,
                                           int* sE, int par, int tid) {
  int i  = tid >> 4;   // row-tile: rows i*4..i*4+3
  int cc = tid & 15;   // col-tile: cols cc*4..cc*4+3
  int sw = i & 3;
  f32x4 acc[4];
  acc[0] = acc[1] = acc[2] = acc[3] = (f32x4){0.f, 0.f, 0.f, 0.f};
#pragma unroll
  for (int p0 = 0; p0 < 16; p0++) {
    f32x4 b0 = Ts4[(p0 * 4 + 0) * 16 + cc];
    f32x4 b1 = Ts4[(p0 * 4 + 1) * 16 + cc];
    f32x4 b2 = Ts4[(p0 * 4 + 2) * 16 + cc];
    f32x4 b3 = Ts4[(p0 * 4 + 3) * 16 + cc];
#pragma unroll
    for (int j = 0; j < 4; j++) {
      f32x4 a = Ms4[(i * 4 + j) * 16 + (p0 ^ sw)];
      acc[j] += a[0] * b0 + a[1] * b1 + a[2] * b2 + a[3] * b3;
    }
  }
  float m = acc[0][0];
#pragma unroll
  for (int j = 0; j < 4; j++)
#pragma unroll
    for (int k = 0; k < 4; k++) m = fmaxf(m, acc[j][k]);
  int e = (int)((__float_as_uint(m) >> 23) & 255u);
  atomicMax(&sE[par], e);
  __syncthreads();
  int eM = sE[par];
  float scale = __uint_as_float((unsigned)(254 - eM) << 23);  // 2^-(eM-127)
#pragma unroll
  for (int j = 0; j < 4; j++)
    Ms4[(i * 4 + j) * 16 + (cc ^ sw)] = acc[j] * scale;
  return (float)(eM - 127);
}

// ---- K4a: per-chunk product of 8 transition matrices -------------------
__global__ __launch_bounds__(256) void crf_chunk_k(
    const float* __restrict__ tm2, const float* __restrict__ be2,
    const int* __restrict__ target,
    float* __restrict__ Mc, float* __restrict__ Lc)
{
  __shared__ f32x4 Ms4[1024];
  __shared__ f32x4 Ts4[1024];
  __shared__ int sE[2];
  int blk = blockIdx.x;          // 0..255
  int b = blk >> 6, c = blk & 63;
  int tid = threadIdx.x;
  if (tid < 2) sE[tid] = 0;
  const float* tmb = tm2 + (size_t)b * 511 * 4096;
  const float* beb = be2 + (size_t)b * TT * 64;
  int t0 = 1 + c * CH;
  int t1 = t0 + CH; if (t1 > TT) t1 = TT;   // steps t0..t1-1 (t in 1..511)
  bool first = true;
  float Lacc = 0.f;
  int par = 0;
  for (int t = t0; t < t1; t++) {
    if (target[b * TT + t] == 0) continue;       // masked: identity step
    if (first) {
      stage_exp(tmb + (size_t)(t - 1) * 4096, beb + t * 64, Ms4, tid, 1);
      first = false;
      continue;
    }
    stage_exp(tmb + (size_t)(t - 1) * 4096, beb + t * 64, Ts4, tid, 0);
    __syncthreads();                 // Ts + previous Ms stores visible
    if (tid == 0) sE[par ^ 1] = 0;   // reset the buffer consumed last step
    Lacc += mm_renorm(Ms4, Ts4, sE, par, tid);
    par ^= 1;
  }
  size_t obase = (size_t)(b * NCH + c) * 4096;
  int r = tid >> 2, c4 = (tid & 3) * 4;
  if (first) {  // whole chunk masked -> identity
#pragma unroll
    for (int q = 0; q < 4; q++) {
      f32x4 o = (f32x4){0.f, 0.f, 0.f, 0.f};
      int cb = (c4 + q) * 4;
      if (r >= cb && r < cb + 4) o[r - cb] = 1.f;
      *(f32x4*)(Mc + obase + r * 64 + cb) = o;
    }
  } else {
    __syncthreads();
    int sw = (r >> 2) & 3;
#pragma unroll
    for (int q = 0; q < 4; q++)
      *(f32x4*)(Mc + obase + r * 64 + (c4 + q) * 4) = Ms4[r * 16 + ((c4 + q) ^ sw)];
  }
  if (tid == 0) Lc[b * NCH + c] = Lacc;
}

// ---- K4b: fold 8 chunk matrices into one super matrix ------------------
__global__ __launch_bounds__(256) void crf_super_k(
    const float* __restrict__ Mc, const float* __restrict__ Lc,
    float* __restrict__ Msup, float* __restrict__ Lsup)
{
  __shared__ f32x4 Ms4[1024];
  __shared__ f32x4 Ts4[1024];
  __shared__ int sE[2];
  int blk = blockIdx.x;          // 0..31
  int b = blk >> 3, s = blk & 7;
  int tid = threadIdx.x;
  if (tid < 2) sE[tid] = 0;
  const float* base = Mc + (size_t)(b * NCH + s * NSUP) * 4096;
  float Lacc = Lc[b * NCH + s * NSUP];
  stage_copy_swz(base, Ms4, tid);
  int par = 0;
  for (int q = 1; q < NSUP; q++) {
#pragma unroll
    for (int ii = 0; ii < 4; ii++) {
      int ci = tid + 256 * ii;
      async_cp16((void*)(Ts4 + ci), base + (size_t)q * 4096 + ci * 4);
    }
    __syncthreads();                 // vmcnt drained; Ms stores visible
    if (tid == 0) sE[par ^ 1] = 0;
    Lacc += mm_renorm(Ms4, Ts4, sE, par, tid);
    Lacc += Lc[b * NCH + s * NSUP + q];
    par ^= 1;
  }
  __syncthreads();
  size_t obase = (size_t)(b * NSUP + s) * 4096;
  int r = tid >> 2, c4 = (tid & 3) * 4;
  int sw = (r >> 2) & 3;
#pragma unroll
  for (int q = 0; q < 4; q++)
    *(f32x4*)(Msup + obase + r * 64 + (c4 + q) * 4) = Ms4[r * 16 + ((c4 + q) ^ sw)];
  if (tid == 0) Lsup[b * NSUP + s] = Lacc;
}

// ---- K4c: numerator + 8 matvec steps + final logsumexp -----------------
__global__ __launch_bounds__(256) void crf_final_k(
    const float* __restrict__ Msup, const float* __restrict__ Lsup,
    const float* __restrict__ be2, const float* __restrict__ emit_tgt,
    const int* __restrict__ target,
    const float* __restrict__ E1, const float* __restrict__ E2,
    float* __restrict__ loss_out)
{
  __shared__ float red[2][4][64];
  __shared__ float nred[256];
  int b = blockIdx.x;
  int tid = threadIdx.x;
  int lane = tid & 63;   // state n
  int pg = tid >> 6;     // prev-state group: p = pg*16 + j

  // numerator (natural-log scale): sum_t mask*(emit + trans)
  float num = 0.f;
  for (int t = tid; t < TT; t += 256) {
    int tcur = target[b * TT + t];
    if (tcur != 0) {
      float s = emit_tgt[b * TT + t];
      if (t >= 1) {
        int tprev = target[b * TT + t - 1];
        const float* r1 = E1 + (size_t)tprev * RANK;
        const float* r2 = E2 + (size_t)tcur * RANK;
        float d = 0.f;
#pragma unroll
        for (int k = 0; k < RANK; k++) d += r1[k] * r2[k];
        s += d;
      }
      num += s;
    }
  }
  nred[tid] = num;
  __syncthreads();
  for (int off = 128; off > 0; off >>= 1) {
    if (tid < off) nred[tid] += nred[tid + off];
    __syncthreads();
  }
  float numerator = nred[0];

  // u = exp2(score0); pads (be2 = -1.44e30) flush to 0 correctly
  float uv = fast_exp2(be2[(size_t)b * TT * 64 + lane]);
  float Ltot = 0.f;
  int par = 0;
  for (int s = 0; s < NSUP; s++) {
    const float* P = Msup + (size_t)(b * NSUP + s) * 4096 + pg * 16 * 64 + lane;
    float part = 0.f;
#pragma unroll
    for (int j = 0; j < 16; j++)
      part += __shfl(uv, pg * 16 + j, 64) * P[j * 64];
    red[par][pg][lane] = part;
    __syncthreads();
    float S = red[par][0][lane] + red[par][1][lane] +
              red[par][2][lane] + red[par][3][lane];
    float m = S;
#pragma unroll
    for (int o = 32; o > 0; o >>= 1) m = fmaxf(m, __shfl_xor(m, o, 64));
    int e = (int)((__float_as_uint(m) >> 23) & 255u);
    float sc = __uint_as_float((unsigned)(254 - e) << 23);
    uv = S * sc;
    Ltot += (float)(e - 127) + Lsup[b * NSUP + s];
    par ^= 1;
  }
  if (pg == 0) {
    float ssum = uv;
#pragma unroll
    for (int o = 32; o > 0; o >>= 1) ssum += __shfl_xor(ssum, o, 64);
    if (lane == 0)
      loss_out[b] = (fast_log2(ssum) + Ltot) * LN2 - numerator;
  }
}

extern "C" void kernel_launch(void* const* d_in, const int* in_sizes, int n_in,
                              void* d_out, int out_size, void* d_ws, size_t ws_size,
                              hipStream_t stream) {
  const float* modelout = (const float*)d_in[0];  // [4,512,1024]
  const float* W        = (const float*)d_in[1];  // [32000,1024]
  const float* bias     = (const float*)d_in[2];  // [32000]
  const float* E1       = (const float*)d_in[3];  // [32000,32]
  const float* E2       = (const float*)d_in[4];  // [32000,32]
  const int*   target   = (const int*)d_in[5];    // [2048]

  float* logits = (float*)d_out;                      // 65,536,000 f32
  float* loss   = (float*)d_out + (size_t)MDIM * VOCAB;  // 4 f32

  char* ws = (char*)d_ws;
  unsigned short* Abf = (unsigned short*)(ws);               // 4 MB
  unsigned short* Wbf = (unsigned short*)(ws + 4194304);     // 62.5 MB
  int*   beam_idx = (int*)  (ws + 69730304);                 // 512 KB
  float* be2      = (float*)(ws + 70254592);                 // 512 KB
  float* emit_tg  = (float*)(ws + 70778880);                 // 8 KB
  float* tm2      = (float*)(ws + 70787072);                 // 32 MB
  // scan workspace reuses the GEMM staging regions (dead after gemm_bt_k):
  float* Mc   = (float*)ws;                       // 4 MB  (= Abf region)
  float* Msup = (float*)(ws + 4194304);           // 512 KB (= Wbf head)
  float* Lc   = (float*)(ws + 4194304 + 524288);  // 1 KB
  float* Lsup = (float*)(ws + 4194304 + 524288 + 1024);  // 128 B

  cvt_bf16_k<<<2048, 256, 0, stream>>>(modelout, Abf, 524288);
  cvt_bf16_k<<<32000, 256, 0, stream>>>(W, Wbf, 8192000);
  gemm_bt_k<<<dim3(250, 16), 256, 0, stream>>>(Abf, Wbf, bias, logits);
  topk_k<<<2048, 256, 0, stream>>>(logits, target, beam_idx, be2, emit_tg);
  trans_k<<<2044, 256, 0, stream>>>(E1, E2, beam_idx, tm2);
  crf_chunk_k<<<256, 256, 0, stream>>>(tm2, be2, target, Mc, Lc);
  crf_super_k<<<32, 256, 0, stream>>>(Mc, Lc, Msup, Lsup);
  crf_final_k<<<4, 256, 0, stream>>>(Msup, Lsup, be2, emit_tg, target, E1, E2, loss);
}

// Round 2
// 720.421 us; speedup vs baseline: 1.3827x; 1.0728x over previous
//
#include <hip/hip_runtime.h>
#include <stdint.h>

#define VOCAB 32000
#define MDIM  2048     // B*T
#define KDIM  1024     // E
#define RANK  32
#define TT    512
#define INV_LN2 1.4426950408889634f
#define LN2     0.6931471805599453f
#define CH    8        // scan steps folded per chunk
#define NCH   64       // chunks per batch (ceil(511/8))
#define NSUP  8        // chunk matrices folded per super matrix

typedef __attribute__((ext_vector_type(8))) __bf16 bf16x8;
typedef __attribute__((ext_vector_type(4))) float f32x4;

__device__ __forceinline__ void async_cp16(void* lds, const void* g) {
  __builtin_amdgcn_global_load_lds(
      (const __attribute__((address_space(1))) void*)g,
      (__attribute__((address_space(3))) void*)lds, 16, 0, 0);
}

__device__ __forceinline__ float fast_exp2(float x) {
#if __has_builtin(__builtin_amdgcn_exp2f)
  return __builtin_amdgcn_exp2f(x);
#else
  return exp2f(x);
#endif
}
__device__ __forceinline__ float fast_log2(float x) {
#if __has_builtin(__builtin_amdgcn_logf)
  return __builtin_amdgcn_logf(x);
#else
  return log2f(x);
#endif
}

__device__ __forceinline__ unsigned short f2bf(float f) {
  unsigned u = __float_as_uint(f);
  unsigned r = (u + 0x7FFFu + ((u >> 16) & 1u)) >> 16;  // RNE
  return (unsigned short)r;
}

// ---------------- K0: f32 -> bf16 convert ----------------
__global__ void cvt_bf16_k(const float* __restrict__ src,
                           unsigned short* __restrict__ dst, int n4) {
  int i = blockIdx.x * blockDim.x + threadIdx.x;
  if (i >= n4) return;
  float4 v = ((const float4*)src)[i];
  ushort4 o;
  o.x = f2bf(v.x); o.y = f2bf(v.y); o.z = f2bf(v.z); o.w = f2bf(v.w);
  ((ushort4*)dst)[i] = o;
}

// ---------------- K1: logits = A @ W^T + b -------------------------------
// 256x256 tile, BK=64, 8 waves (2Mx4N), 512 thr, 128 KiB LDS double-buffer.
// 8-phase schedule (T3+T4): 2 K-tiles/iter, 1 half-tile staged per phase,
// counted vmcnt(4) at phases 4/8 only, raw s_barrier (no vmcnt0 drain),
// setprio around MFMA clusters (T5), XOR LDS swizzle via pre-swizzled
// global source (T2, rule-21 both-sides), bijective XCD block swizzle (T1).
//
// LDS element (row r, col-group g of 8 bf16) holds global col-group
// g ^ (r & 7)  -> ds_read_b128 of 16 rows x same col spreads across all
// 32 banks (2-way residue = free).
//
// Stage map per iteration i (K-tiles 2i in buf0, 2i+1 in buf1), derived
// from region-free times (B-frags hoisted at phase 0 of each K-tile):
//   ph0: buf1.A0<-kt(2i+1)  ph1: buf1.A1      [buf1.A freed ph7 prev iter]
//   ph2: buf0.B0<-kt(2i+2)  ph3: buf0.B1 +vmcnt(4)  [buf0.B freed ph0]
//   ph4: buf0.A0<-kt(2i+2)  ph5: buf0.A1      [buf0.A freed ph3]
//   ph6: buf1.B0<-kt(2i+3)  ph7: buf1.B1 +vmcnt(4)  [buf1.B freed ph4]
// vmcnt(4) at ph3 lands kt(2i+1) fully (leaves kt(2i+2).B in flight);
// vmcnt(4) at ph7 lands kt(2i+2) fully (leaves kt(2i+3).B in flight).

#define STG_A(BUF, KT, HALF)                                              \
  {                                                                       \
    _Pragma("unroll")                                                     \
    for (int ii = 0; ii < 2; ii++) {                                      \
      int ci = tid + 512 * ii;                                            \
      int r  = ci >> 3;                                                   \
      int g  = ci & 7;                                                    \
      async_cp16(&As[BUF][(HALF) * 8192 + ci * 8],                        \
                 Ag + (size_t)((HALF) * 128 + r) * KDIM + (KT) * 64 +     \
                     ((g ^ (r & 7)) << 3));                               \
    }                                                                     \
  }

#define STG_B(BUF, KT, HALF)                                              \
  {                                                                       \
    _Pragma("unroll")                                                     \
    for (int ii = 0; ii < 2; ii++) {                                      \
      int ci = tid + 512 * ii;                                            \
      int r  = ci >> 3;                                                   \
      int g  = ci & 7;                                                    \
      async_cp16(&Bs[BUF][(HALF) * 8192 + ci * 8],                        \
                 Bg + (size_t)((HALF) * 128 + r) * KDIM + (KT) * 64 +     \
                     ((g ^ (r & 7)) << 3));                               \
    }                                                                     \
  }

#define READS(BUF, MI0, LOADB)                                            \
    if (LOADB) {                                                          \
      _Pragma("unroll")                                                   \
      for (int ni = 0; ni < 4; ni++) {                                    \
        int n_ = wn * 64 + ni * 16 + (lane & 15);                         \
        int sx = n_ & 7;                                                  \
        bfr[ni][0] = *(const bf16x8*)&Bs[BUF][n_ * 64 + ((ls ^ sx) << 3)];       \
        bfr[ni][1] = *(const bf16x8*)&Bs[BUF][n_ * 64 + (((ls + 4) ^ sx) << 3)]; \
      }                                                                   \
    }                                                                     \
    {                                                                     \
      int m_ = wm * 128 + (MI0) * 16 + (lane & 15);                       \
      int sx = m_ & 7;                                                    \
      a0[0] = *(const bf16x8*)&As[BUF][m_ * 64 + ((ls ^ sx) << 3)];       \
      a0[1] = *(const bf16x8*)&As[BUF][m_ * 64 + (((ls + 4) ^ sx) << 3)]; \
      int m2 = m_ + 16;                                                   \
      a1[0] = *(const bf16x8*)&As[BUF][m2 * 64 + ((ls ^ sx) << 3)];       \
      a1[1] = *(const bf16x8*)&As[BUF][m2 * 64 + (((ls + 4) ^ sx) << 3)]; \
    }

#define MMA16(MI0)                                                        \
    _Pragma("unroll")                                                     \
    for (int ni = 0; ni < 4; ni++) {                                      \
      acc[MI0][ni] = __builtin_amdgcn_mfma_f32_16x16x32_bf16(             \
          a0[0], bfr[ni][0], acc[MI0][ni], 0, 0, 0);                      \
      acc[MI0][ni] = __builtin_amdgcn_mfma_f32_16x16x32_bf16(             \
          a0[1], bfr[ni][1], acc[MI0][ni], 0, 0, 0);                      \
      acc[(MI0) + 1][ni] = __builtin_amdgcn_mfma_f32_16x16x32_bf16(       \
          a1[0], bfr[ni][0], acc[(MI0) + 1][ni], 0, 0, 0);                \
      acc[(MI0) + 1][ni] = __builtin_amdgcn_mfma_f32_16x16x32_bf16(       \
          a1[1], bfr[ni][1], acc[(MI0) + 1][ni], 0, 0, 0);                \
    }

#define PHASE(BUF, MI0, LOADB, STAGE_CODE, WAIT_CODE)                     \
  do {                                                                    \
    bf16x8 a0[2], a1[2];                                                  \
    READS(BUF, MI0, LOADB)                                                \
    STAGE_CODE                                                            \
    __builtin_amdgcn_s_barrier();                                         \
    asm volatile("s_waitcnt lgkmcnt(0)" ::: "memory");                    \
    __builtin_amdgcn_sched_barrier(0);                                    \
    __builtin_amdgcn_s_setprio(1);                                        \
    MMA16(MI0)                                                            \
    __builtin_amdgcn_s_setprio(0);                                        \
    WAIT_CODE                                                             \
    __builtin_amdgcn_s_barrier();                                         \
    __builtin_amdgcn_sched_barrier(0);                                    \
  } while (0);

__global__ __launch_bounds__(512, 2) void gemm_bt_k(
    const unsigned short* __restrict__ A,   // [2048][1024] bf16
    const unsigned short* __restrict__ Bw,  // [32000][1024] bf16
    const float* __restrict__ bias,
    float* __restrict__ C)                  // [2048][32000] f32
{
  __shared__ unsigned short As[2][16384];   // [buf][256 rows x 64 cols]
  __shared__ unsigned short Bs[2][16384];
  int tid  = threadIdx.x;
  int lane = tid & 63;
  int wave = tid >> 6;
  int wm = wave >> 2, wn = wave & 3;
  int ls = lane >> 4;

  // T1: XCD-contiguous work chunks (1000 = 8 XCD * 125, bijective)
  int bid = blockIdx.x;
  int w   = (bid & 7) * 125 + (bid >> 3);
  int bm  = w & 7, bn = w >> 3;   // bm fastest: A panel reused within XCD
  int m0 = bm << 8, n0 = bn << 8;

  const unsigned short* Ag = A  + (size_t)m0 * KDIM;
  const unsigned short* Bg = Bw + (size_t)n0 * KDIM;

  f32x4 acc[8][4];
#pragma unroll
  for (int i = 0; i < 8; i++)
#pragma unroll
    for (int j = 0; j < 4; j++) acc[i][j] = (f32x4){0.f, 0.f, 0.f, 0.f};
  bf16x8 bfr[4][2];

  // prologue: kt0.B, kt0.A, kt1.B (12 loads); wait kt0 landed, kt1.B flying
  STG_B(0, 0, 0) STG_B(0, 0, 1)
  STG_A(0, 0, 0) STG_A(0, 0, 1)
  STG_B(1, 1, 0) STG_B(1, 1, 1)
  asm volatile("s_waitcnt vmcnt(4)" ::: "memory");
  __builtin_amdgcn_s_barrier();
  __builtin_amdgcn_sched_barrier(0);

#pragma unroll 1
  for (int i = 0; i < 8; i++) {
    int kt1 = 2 * i + 1, kt2 = 2 * i + 2, kt3 = 2 * i + 3;
    bool st = (i < 7);
    PHASE(0, 0, 1, { STG_A(1, kt1, 0) }, {})
    PHASE(0, 2, 0, { STG_A(1, kt1, 1) }, {})
    PHASE(0, 4, 0, { if (st) STG_B(0, kt2, 0) }, {})
    PHASE(0, 6, 0, { if (st) STG_B(0, kt2, 1) },
          { if (st) { asm volatile("s_waitcnt vmcnt(4)" ::: "memory"); }
            else    { asm volatile("s_waitcnt vmcnt(0)" ::: "memory"); } })
    PHASE(1, 0, 1, { if (st) STG_A(0, kt2, 0) }, {})
    PHASE(1, 2, 0, { if (st) STG_A(0, kt2, 1) }, {})
    PHASE(1, 4, 0, { if (st) STG_B(1, kt3, 0) }, {})
    PHASE(1, 6, 0, { if (st) STG_B(1, kt3, 1) },
          { asm volatile("s_waitcnt vmcnt(4)" ::: "memory"); })
  }

  // epilogue: C/D layout col=lane&15, row=(lane>>4)*4+reg  [m89-verified]
  int cl = lane & 15;
  int rq = ls * 4;
  float bv[4];
#pragma unroll
  for (int ni = 0; ni < 4; ni++) bv[ni] = bias[n0 + wn * 64 + ni * 16 + cl];
#pragma unroll
  for (int mi = 0; mi < 8; mi++) {
#pragma unroll
    for (int r = 0; r < 4; r++) {
      int m = m0 + wm * 128 + mi * 16 + rq + r;
      float* Crow = C + (size_t)m * VOCAB + n0 + wn * 64;
#pragma unroll
      for (int ni = 0; ni < 4; ni++)
        Crow[ni * 16 + cl] = acc[mi][ni][r] + bv[ni];
    }
  }
}

// ---------------- K2: top-64 per row, target forced ----------------
#define CAP 1024
__global__ __launch_bounds__(256) void topk_k(
    const float* __restrict__ logits, const int* __restrict__ target,
    int* __restrict__ beam_idx, float* __restrict__ beam_emit2,
    float* __restrict__ emit_tgt)
{
  __shared__ unsigned long long packs[CAP];
  __shared__ int ncand;
  int r   = blockIdx.x;  // 0..2047 = b*512+t
  int tid = threadIdx.x;
  const float* row = logits + (size_t)r * VOCAB;
  int tgt = target[r];
  if (tid == 0) ncand = 0;
  for (int i = tid; i < CAP; i += 256) packs[i] = 0ull;
  __syncthreads();

  const float TH = 1.45f;
  for (int i = tid * 4; i < VOCAB; i += 1024) {
    float4 v = *(const float4*)(row + i);
#pragma unroll
    for (int j = 0; j < 4; j++) {
      float f = (&v.x)[j];
      int idx = i + j;
      if (f > TH || idx == tgt) {
        unsigned key = __float_as_uint(f);
        key = (key & 0x80000000u) ? ~key : (key | 0x80000000u);
        if (idx == tgt) key = 0xFFFFFFFFu;  // forced inf
        int p = atomicAdd(&ncand, 1);
        if (p < CAP) packs[p] = ((unsigned long long)key << 32) | (unsigned)idx;
      }
    }
  }
  __syncthreads();
  // bitonic sort descending (pad key 0 sorts last)
  for (unsigned k = 2; k <= CAP; k <<= 1) {
    for (unsigned j = k >> 1; j > 0; j >>= 1) {
      for (int i = tid; i < CAP; i += 256) {
        int ixj = i ^ (int)j;
        if (ixj > i) {
          unsigned long long a = packs[i], c = packs[ixj];
          bool up = ((i & k) == 0);
          if (up ? (a < c) : (a > c)) { packs[i] = c; packs[ixj] = a; }
        }
      }
      __syncthreads();
    }
  }
  if (tid < 64) {
    unsigned long long pk = packs[tid];
    unsigned key = (unsigned)(pk >> 32);
    int idx = (int)(pk & 0xFFFFFFFFu);
    float v;
    if (key == 0xFFFFFFFFu) v = row[tgt];          // true logit at target
    else if (key == 0u)     { v = -1e30f; idx = 0; }  // impossible pad
    else {
      unsigned u = (key & 0x80000000u) ? (key & 0x7FFFFFFFu) : ~key;
      v = __uint_as_float(u);
    }
    beam_idx[r * 64 + tid]  = idx;
    beam_emit2[r * 64 + tid] = v * INV_LN2;  // log2 domain
  }
  if (tid == 0) emit_tgt[r] = row[tgt];
}

// ---------------- K3: tm2[b][t-1][p][n] = dot(E1[beam(t-1,p)], E2[beam(t,n)])/ln2
__global__ __launch_bounds__(256) void trans_k(
    const float* __restrict__ E1, const float* __restrict__ E2,
    const int* __restrict__ beam_idx, float* __restrict__ tm2)
{
  __shared__ float e1[64][33];  // +1 pad: conflict-free column reads
  __shared__ float e2[64][33];
  int x = blockIdx.x;            // 0..2043
  int b = x / 511;
  int t = 1 + (x % 511);
  int tid = threadIdx.x;
  {
    int rowi = tid >> 2, seg = tid & 3;
    int i1 = beam_idx[(b * TT + (t - 1)) * 64 + rowi];
    int i2 = beam_idx[(b * TT + t) * 64 + rowi];
    const float4* p1 = (const float4*)(E1 + (size_t)i1 * RANK);
    const float4* p2 = (const float4*)(E2 + (size_t)i2 * RANK);
    float4 a0 = p1[seg * 2], a1 = p1[seg * 2 + 1];
    float4 c0 = p2[seg * 2], c1 = p2[seg * 2 + 1];
    int c = seg * 8;
    e1[rowi][c+0]=a0.x; e1[rowi][c+1]=a0.y; e1[rowi][c+2]=a0.z; e1[rowi][c+3]=a0.w;
    e1[rowi][c+4]=a1.x; e1[rowi][c+5]=a1.y; e1[rowi][c+6]=a1.z; e1[rowi][c+7]=a1.w;
    e2[rowi][c+0]=c0.x; e2[rowi][c+1]=c0.y; e2[rowi][c+2]=c0.z; e2[rowi][c+3]=c0.w;
    e2[rowi][c+4]=c1.x; e2[rowi][c+5]=c1.y; e2[rowi][c+6]=c1.z; e2[rowi][c+7]=c1.w;
  }
  __syncthreads();
  int n = tid & 63;
  float re2[RANK];
#pragma unroll
  for (int k = 0; k < RANK; k++) re2[k] = e2[n][k];
  float* out = tm2 + (size_t)(b * 511 + (t - 1)) * 4096;
#pragma unroll
  for (int i = 0; i < 16; i++) {
    int p = (tid >> 6) * 16 + i;   // wave-uniform -> LDS broadcast
    float s = 0.f;
#pragma unroll
    for (int k = 0; k < RANK; k++) s += e1[p][k] * re2[k];
    out[p * 64 + n] = s * INV_LN2;
  }
}

// ====================== K4: parallel CRF scan ===========================
// logsumexp recurrence = associative scan under max-rescaled exp-domain
// matrix product.  K4a: 256 blocks fold 8 steps -> chunk matrix;
// K4b: 32 blocks fold 8 chunks -> super matrices; K4c: 4 blocks finish.

__device__ __forceinline__ void stage_exp(const float* __restrict__ tmrow,
                                          const float* __restrict__ berow,
                                          f32x4* dst4, int tid, int swz) {
  int r  = tid >> 2;
  int c4 = (tid & 3) * 4;
  int sw = swz ? ((r >> 2) & 3) : 0;
  const f32x4* src  = (const f32x4*)(tmrow + r * 64);
  const f32x4* bsrc = (const f32x4*)berow;
#pragma unroll
  for (int q = 0; q < 4; q++) {
    f32x4 v  = src[c4 + q];
    f32x4 be = bsrc[c4 + q];
    f32x4 o;
    o[0] = fast_exp2(v[0] + be[0]);
    o[1] = fast_exp2(v[1] + be[1]);
    o[2] = fast_exp2(v[2] + be[2]);
    o[3] = fast_exp2(v[3] + be[3]);
    dst4[r * 16 + ((c4 + q) ^ sw)] = o;
  }
}

__device__ __forceinline__ void stage_copy_swz(const float* __restrict__ src,
                                               f32x4* dst4, int tid) {
  int r  = tid >> 2;
  int c4 = (tid & 3) * 4;
  int sw = (r >> 2) & 3;
  const f32x4* s4 = (const f32x4*)(src + r * 64);
#pragma unroll
  for (int q = 0; q < 4; q++) dst4[r * 16 + ((c4 + q) ^ sw)] = s4[c4 + q];
}

// Ms <- renorm(Ms @ Ts); returns log2 scale consumed.
__device__ __forceinline__ float mm_renorm(f32x4* Ms4, const f32x4* Ts4,
                                           int* sE, int par, int tid) {
  int i  = tid >> 4;   // row-tile: rows i*4..i*4+3
  int cc = tid & 15;   // col-tile: cols cc*4..cc*4+3
  int sw = i & 3;
  f32x4 acc[4];
  acc[0] = acc[1] = acc[2] = acc[3] = (f32x4){0.f, 0.f, 0.f, 0.f};
#pragma unroll
  for (int p0 = 0; p0 < 16; p0++) {
    f32x4 b0 = Ts4[(p0 * 4 + 0) * 16 + cc];
    f32x4 b1 = Ts4[(p0 * 4 + 1) * 16 + cc];
    f32x4 b2 = Ts4[(p0 * 4 + 2) * 16 + cc];
    f32x4 b3 = Ts4[(p0 * 4 + 3) * 16 + cc];
#pragma unroll
    for (int j = 0; j < 4; j++) {
      f32x4 a = Ms4[(i * 4 + j) * 16 + (p0 ^ sw)];
      acc[j] += a[0] * b0 + a[1] * b1 + a[2] * b2 + a[3] * b3;
    }
  }
  float m = acc[0][0];
#pragma unroll
  for (int j = 0; j < 4; j++)
#pragma unroll
    for (int k = 0; k < 4; k++) m = fmaxf(m, acc[j][k]);
  int e = (int)((__float_as_uint(m) >> 23) & 255u);
  atomicMax(&sE[par], e);
  __syncthreads();
  int eM = sE[par];
  float scale = __uint_as_float((unsigned)(254 - eM) << 23);  // 2^-(eM-127)
#pragma unroll
  for (int j = 0; j < 4; j++)
    Ms4[(i * 4 + j) * 16 + (cc ^ sw)] = acc[j] * scale;
  return (float)(eM - 127);
}

// ---- K4a: per-chunk product of 8 transition matrices -------------------
__global__ __launch_bounds__(256) void crf_chunk_k(
    const float* __restrict__ tm2, const float* __restrict__ be2,
    const int* __restrict__ target,
    float* __restrict__ Mc, float* __restrict__ Lc)
{
  __shared__ f32x4 Ms4[1024];
  __shared__ f32x4 Ts4[1024];
  __shared__ int sE[2];
  int blk = blockIdx.x;          // 0..255
  int b = blk >> 6, c = blk & 63;
  int tid = threadIdx.x;
  if (tid < 2) sE[tid] = 0;
  const float* tmb = tm2 + (size_t)b * 511 * 4096;
  const float* beb = be2 + (size_t)b * TT * 64;
  int t0 = 1 + c * CH;
  int t1 = t0 + CH; if (t1 > TT) t1 = TT;   // steps t0..t1-1 (t in 1..511)
  bool first = true;
  float Lacc = 0.f;
  int par = 0;
  for (int t = t0; t < t1; t++) {
    if (target[b * TT + t] == 0) continue;       // masked: identity step
    if (first) {
      stage_exp(tmb + (size_t)(t - 1) * 4096, beb + t * 64, Ms4, tid, 1);
      first = false;
      continue;
    }
    stage_exp(tmb + (size_t)(t - 1) * 4096, beb + t * 64, Ts4, tid, 0);
    __syncthreads();                 // Ts + previous Ms stores visible
    if (tid == 0) sE[par ^ 1] = 0;   // reset the buffer consumed last step
    Lacc += mm_renorm(Ms4, Ts4, sE, par, tid);
    par ^= 1;
  }
  size_t obase = (size_t)(b * NCH + c) * 4096;
  int r = tid >> 2, c4 = (tid & 3) * 4;
  if (first) {  // whole chunk masked -> identity
#pragma unroll
    for (int q = 0; q < 4; q++) {
      f32x4 o = (f32x4){0.f, 0.f, 0.f, 0.f};
      int cb = (c4 + q) * 4;
      if (r >= cb && r < cb + 4) o[r - cb] = 1.f;
      *(f32x4*)(Mc + obase + r * 64 + cb) = o;
    }
  } else {
    __syncthreads();
    int sw = (r >> 2) & 3;
#pragma unroll
    for (int q = 0; q < 4; q++)
      *(f32x4*)(Mc + obase + r * 64 + (c4 + q) * 4) = Ms4[r * 16 + ((c4 + q) ^ sw)];
  }
  if (tid == 0) Lc[b * NCH + c] = Lacc;
}

// ---- K4b: fold 8 chunk matrices into one super matrix ------------------
__global__ __launch_bounds__(256) void crf_super_k(
    const float* __restrict__ Mc, const float* __restrict__ Lc,
    float* __restrict__ Msup, float* __restrict__ Lsup)
{
  __shared__ f32x4 Ms4[1024];
  __shared__ f32x4 Ts4[1024];
  __shared__ int sE[2];
  int blk = blockIdx.x;          // 0..31
  int b = blk >> 3, s = blk & 7;
  int tid = threadIdx.x;
  if (tid < 2) sE[tid] = 0;
  const float* base = Mc + (size_t)(b * NCH + s * NSUP) * 4096;
  float Lacc = Lc[b * NCH + s * NSUP];
  stage_copy_swz(base, Ms4, tid);
  int par = 0;
  for (int q = 1; q < NSUP; q++) {
#pragma unroll
    for (int ii = 0; ii < 4; ii++) {
      int ci = tid + 256 * ii;
      async_cp16((void*)(Ts4 + ci), base + (size_t)q * 4096 + ci * 4);
    }
    __syncthreads();                 // vmcnt drained; Ms stores visible
    if (tid == 0) sE[par ^ 1] = 0;
    Lacc += mm_renorm(Ms4, Ts4, sE, par, tid);
    Lacc += Lc[b * NCH + s * NSUP + q];
    par ^= 1;
  }
  __syncthreads();
  size_t obase = (size_t)(b * NSUP + s) * 4096;
  int r = tid >> 2, c4 = (tid & 3) * 4;
  int sw = (r >> 2) & 3;
#pragma unroll
  for (int q = 0; q < 4; q++)
    *(f32x4*)(Msup + obase + r * 64 + (c4 + q) * 4) = Ms4[r * 16 + ((c4 + q) ^ sw)];
  if (tid == 0) Lsup[b * NSUP + s] = Lacc;
}

// ---- K4c: numerator + 8 matvec steps + final logsumexp -----------------
__global__ __launch_bounds__(256) void crf_final_k(
    const float* __restrict__ Msup, const float* __restrict__ Lsup,
    const float* __restrict__ be2, const float* __restrict__ emit_tgt,
    const int* __restrict__ target,
    const float* __restrict__ E1, const float* __restrict__ E2,
    float* __restrict__ loss_out)
{
  __shared__ float red[2][4][64];
  __shared__ float nred[256];
  int b = blockIdx.x;
  int tid = threadIdx.x;
  int lane = tid & 63;   // state n
  int pg = tid >> 6;     // prev-state group: p = pg*16 + j

  // numerator (natural-log scale): sum_t mask*(emit + trans)
  float num = 0.f;
  for (int t = tid; t < TT; t += 256) {
    int tcur = target[b * TT + t];
    if (tcur != 0) {
      float s = emit_tgt[b * TT + t];
      if (t >= 1) {
        int tprev = target[b * TT + t - 1];
        const float* r1 = E1 + (size_t)tprev * RANK;
        const float* r2 = E2 + (size_t)tcur * RANK;
        float d = 0.f;
#pragma unroll
        for (int k = 0; k < RANK; k++) d += r1[k] * r2[k];
        s += d;
      }
      num += s;
    }
  }
  nred[tid] = num;
  __syncthreads();
  for (int off = 128; off > 0; off >>= 1) {
    if (tid < off) nred[tid] += nred[tid + off];
    __syncthreads();
  }
  float numerator = nred[0];

  // u = exp2(score0); pads (be2 = -1.44e30) flush to 0 correctly
  float uv = fast_exp2(be2[(size_t)b * TT * 64 + lane]);
  float Ltot = 0.f;
  int par = 0;
  for (int s = 0; s < NSUP; s++) {
    const float* P = Msup + (size_t)(b * NSUP + s) * 4096 + pg * 16 * 64 + lane;
    float part = 0.f;
#pragma unroll
    for (int j = 0; j < 16; j++)
      part += __shfl(uv, pg * 16 + j, 64) * P[j * 64];
    red[par][pg][lane] = part;
    __syncthreads();
    float S = red[par][0][lane] + red[par][1][lane] +
              red[par][2][lane] + red[par][3][lane];
    float m = S;
#pragma unroll
    for (int o = 32; o > 0; o >>= 1) m = fmaxf(m, __shfl_xor(m, o, 64));
    int e = (int)((__float_as_uint(m) >> 23) & 255u);
    float sc = __uint_as_float((unsigned)(254 - e) << 23);
    uv = S * sc;
    Ltot += (float)(e - 127) + Lsup[b * NSUP + s];
    par ^= 1;
  }
  if (pg == 0) {
    float ssum = uv;
#pragma unroll
    for (int o = 32; o > 0; o >>= 1) ssum += __shfl_xor(ssum, o, 64);
    if (lane == 0)
      loss_out[b] = (fast_log2(ssum) + Ltot) * LN2 - numerator;
  }
}

extern "C" void kernel_launch(void* const* d_in, const int* in_sizes, int n_in,
                              void* d_out, int out_size, void* d_ws, size_t ws_size,
                              hipStream_t stream) {
  const float* modelout = (const float*)d_in[0];  // [4,512,1024]
  const float* W        = (const float*)d_in[1];  // [32000,1024]
  const float* bias     = (const float*)d_in[2];  // [32000]
  const float* E1       = (const float*)d_in[3];  // [32000,32]
  const float* E2       = (const float*)d_in[4];  // [32000,32]
  const int*   target   = (const int*)d_in[5];    // [2048]

  float* logits = (float*)d_out;                      // 65,536,000 f32
  float* loss   = (float*)d_out + (size_t)MDIM * VOCAB;  // 4 f32

  char* ws = (char*)d_ws;
  unsigned short* Abf = (unsigned short*)(ws);               // 4 MB
  unsigned short* Wbf = (unsigned short*)(ws + 4194304);     // 62.5 MB
  int*   beam_idx = (int*)  (ws + 69730304);                 // 512 KB
  float* be2      = (float*)(ws + 70254592);                 // 512 KB
  float* emit_tg  = (float*)(ws + 70778880);                 // 8 KB
  float* tm2      = (float*)(ws + 70787072);                 // 32 MB
  // scan workspace reuses the GEMM staging regions (dead after gemm_bt_k):
  float* Mc   = (float*)ws;                       // 4 MB  (= Abf region)
  float* Msup = (float*)(ws + 4194304);           // 512 KB (= Wbf head)
  float* Lc   = (float*)(ws + 4194304 + 524288);  // 1 KB
  float* Lsup = (float*)(ws + 4194304 + 524288 + 1024);  // 128 B

  cvt_bf16_k<<<2048, 256, 0, stream>>>(modelout, Abf, 524288);
  cvt_bf16_k<<<32000, 256, 0, stream>>>(W, Wbf, 8192000);
  gemm_bt_k<<<1000, 512, 0, stream>>>(Abf, Wbf, bias, logits);
  topk_k<<<2048, 256, 0, stream>>>(logits, target, beam_idx, be2, emit_tg);
  trans_k<<<2044, 256, 0, stream>>>(E1, E2, beam_idx, tm2);
  crf_chunk_k<<<256, 256, 0, stream>>>(tm2, be2, target, Mc, Lc);
  crf_super_k<<<32, 256, 0, stream>>>(Mc, Lc, Msup, Lsup);
  crf_final_k<<<4, 256, 0, stream>>>(Msup, Lsup, be2, emit_tg, target, E1, E2, loss);
}